// Round 17
// baseline (502.245 us; speedup 1.0000x reference)
//
#include <hip/hip_runtime.h>

// CANet fused kernel, round 22.
// Post-mortem r21: LDS-op cut worked (conflicts 10.5->6.3M, -31% ops, no
// spill) but bound(256,2) cost occupancy 29.7->22% -> dur 116->155.8.
// Occupancy law refined: flat >=2.4 blocks/CU, proportional below (knee).
// Surviving hypothesis: LDS-op cuts pay ONLY with occupancy held >=2.4.
// r22 = r17 + 4-way M-reuse on G2 ONLY at bound(256,3):
//   G1 unchanged (w1f[2][4]=32 regs, r17 permch);
//   G2: wave(wc=wv>>1,wp=wv&1) owns 64ch x 32px, w2f[4][4]=64 regs,
//   permch64 on w2 rows (d0..d3 -> chs wc*64+16q..+15 -> 2 uint4 writes).
//   Frag regs 96, peak ~160 < 170 (3 waves/SIMD) -> no spill, occ ~30%.
//   G2 B-reads 64->32/blk-iter; total LDS ops 208->176 (-15%).
// Canaries (gating): WRITE 49152KB flat (spill) + Occupancy ~30% (bound).
// Predict: conflicts ~8-9.5M; dur 116 -> 106-112 if LDS-at-knee holds.
// If dur flat with clean canaries: model falsified -> r17 plateau declared.

#define ACT_S 136     // 272 B rows (16B-aligned) for bufA/h1S [px][ch]
#define NOISE_BASE 9437184   // 16*9*65536

// d_ws shorts: Wf[128][128]@0, w2[128][128]@16384, w3[16][128]@32768 (2048)
// floats @ WSF_OFF: b1'[128]@0, b2[128]@128, emb[48]@256
#define WSF_OFF 17408
#define WSF_B1 0
#define WSF_B2 128
#define WSF_EMB 256

typedef short bf16x8 __attribute__((ext_vector_type(8)));
typedef float f32x4 __attribute__((ext_vector_type(4)));

__device__ __forceinline__ short f2bf(float f) {
    union { float f; unsigned u; } cv; cv.f = f;
    unsigned r = cv.u + 0x7FFFu + ((cv.u >> 16) & 1u);
    return (short)(r >> 16);
}
// pack two fp32 -> dword of two bf16 (round-half-up): lo16=bf(f0), hi16=bf(f1)
__device__ __forceinline__ unsigned pk2bf(float f0, float f1) {
    union { float f; unsigned u; } a, b; a.f = f0; b.f = f1;
    return __builtin_amdgcn_perm(b.u + 0x8000u, a.u + 0x8000u, 0x07060302u);
}

// G1 perm (within each 32-ch wave block): f=base+16j+i -> o=base+8(i>>2)+4j+(i&3)
__device__ __forceinline__ int permch(int f) {
    return (f & ~31) + 8 * ((f & 15) >> 2) + 4 * ((f >> 4) & 1) + (f & 3);
}
// G2 perm (within each 64-ch wave half): f=base+16jt+4q+r -> o=base+16q+4jt+r
__device__ __forceinline__ int permch64(int f) {
    return (f & ~63) + 16 * ((f >> 2) & 3) + 4 * ((f >> 4) & 3) + (f & 3);
}

// ---------------- weight prep (fused Wf/b1') + time embedding ----------------
__global__ void prep_emb_kernel(const float* __restrict__ wpg, const float* __restrict__ bpg,
                                const float* __restrict__ w1g, const float* __restrict__ b1g,
                                const float* __restrict__ w2g, const float* __restrict__ b2g,
                                const float* __restrict__ w3g,
                                const int* __restrict__ t,
                                const float* __restrict__ wt, const float* __restrict__ bt,
                                short* __restrict__ wsb, float* __restrict__ wsf)
{
    const int bid = blockIdx.x, tid = threadIdx.x;
    if (bid < 64) {                       // Wf fragment rows (permch out-ch)
        int i = bid * 256 + tid;
        int f = i >> 7, kk = i & 127;
        int o = permch(f);
        int qq = kk >> 5, r = kk & 31;
        float v = 0.f;
        if (r < 30 && (r % 10) < 9) {
            int c3 = r / 10, k = r % 10;
            int ic = 3 * qq + c3;
            #pragma unroll
            for (int j = 0; j < 4; ++j)
                v += w1g[o * 48 + 4 * ic + j] * wpg[(4 * ic + j) * 9 + k];
        }
        wsb[i] = f2bf(v);
        return;
    }
    if (bid < 128) {                      // w2 fragment rows (permch64 out-ch)
        int i = (bid - 64) * 256 + tid;
        int f = i >> 7, col = i & 127;
        wsb[16384 + i] = f2bf(w2g[permch64(f) * 128 + col]);
        return;
    }
    if (bid == 128) {                     // w3 [12][128] -> [16][128] pad
        for (int j = tid; j < 2048; j += 256)
            wsb[32768 + j] = (j < 1536) ? f2bf(w3g[j]) : (short)0;
        return;
    }
    if (bid == 129) {                     // b1' = b1 + w1.bp ; b2 copy (identity)
        if (tid < 128) {
            float s = b1g[tid];
            #pragma unroll 4
            for (int c = 0; c < 48; ++c) s += w1g[tid * 48 + c] * bpg[c];
            wsf[WSF_B1 + tid] = s;
        } else {
            wsf[WSF_B2 + (tid - 128)] = b2g[tid - 128];
        }
        return;
    }
    int b = bid - 130;                    // time embedding, one block per batch
    int lane = threadIdx.x;
    if (lane >= 64) return;
    float tv = (float)t[b];
    float s0 = 0.f, s1 = 0.f, s2 = 0.f;
    const float LOG1E4 = 9.210340371976184f;
    #pragma unroll
    for (int ii = 0; ii < 2; ++ii) {
        int i = lane + ii * 64;
        float invf = __expf(-LOG1E4 * (float)i * (1.0f / 128.0f));
        float ang = tv * invf;
        float sn = sinf(ang), cs = cosf(ang);
        float ss = sn / (1.0f + __expf(-sn));
        float sc = cs / (1.0f + __expf(-cs));
        s0 += ss * wt[0 * 256 + i] + sc * wt[0 * 256 + i + 128];
        s1 += ss * wt[1 * 256 + i] + sc * wt[1 * 256 + i + 128];
        s2 += ss * wt[2 * 256 + i] + sc * wt[2 * 256 + i + 128];
    }
    #pragma unroll
    for (int off = 32; off; off >>= 1) {
        s0 += __shfl_down(s0, off);
        s1 += __shfl_down(s1, off);
        s2 += __shfl_down(s2, off);
    }
    if (lane == 0) {
        wsf[WSF_EMB + b * 3 + 0] = s0 + bt[0];
        wsf[WSF_EMB + b * 3 + 1] = s1 + bt[1];
        wsf[WSF_EMB + b * 3 + 2] = s2 + bt[2];
    }
}

// ---------------- main fused kernel ----------------
// MFMA 16x16x32 (m89): A lane(i=lane&15,q) holds A[i][q*8+j]; B symmetric.
// D: col(N)=lane&15, row(M)=q*4+r.
// G1: wave wv owns ch-slice [wv*32,+32) x all 64 px (r17 scheme, permch).
// G2: wave (wc=wv>>1,wp=wv&1) owns ch half [wc*64,+64) x px half [wp*32,+32)
//     (r21 scheme, permch64): 4 M-tiles x 2 N-tiles, 4-way B reuse.
__global__ __launch_bounds__(256, 3) void canet_main(
    const float* __restrict__ xg,   // (16,3,256,256)
    const float* __restrict__ hg,   // (16,9,256,256)
    const short* __restrict__ wsb,
    const float* __restrict__ wsf,
    float* __restrict__ outg)
{
    __shared__ __align__(16) short bufA[64 * ACT_S];   // im2col / h2
    __shared__ __align__(16) short h1S[64 * ACT_S];
    __shared__ __align__(16) short w3_s[16 * 128];     // [oc pad16][k], col XOR-swizzled
    __shared__ __align__(16) float bias_s[256];        // b1' @0, b2 @128

    const int tid = threadIdx.x;
    const int b = blockIdx.x >> 8;
    const int y = blockIdx.x & 255;

    bias_s[tid] = wsf[WSF_B1 + tid];                   // b1'[0:128], b2[128:256]
    for (int i = tid; i < 2048; i += 256) {            // w3 [16][128] swizzled
        int row = i >> 7, col = i & 127;
        w3_s[(row << 7) + (col ^ ((row & 7) << 3))] = wsb[32768 + i];
    }

    const int wv = tid >> 6;
    const int lane = tid & 63;
    const int m = lane & 15;
    const int q = lane >> 4;
    const int wc = wv >> 1;          // G2 ch half
    const int wp = wv & 1;           // G2 px half

    // ---- persistent weight fragments (Wf 32 + w2 64 = 96 regs) ----
    bf16x8 w1f[2][4], w2f[4][4];
    #pragma unroll
    for (int j = 0; j < 2; ++j) {
        int n = wv * 32 + j * 16 + m;
        #pragma unroll
        for (int ks = 0; ks < 4; ++ks)
            w1f[j][ks] = *(const bf16x8*)(wsb + n * 128 + ks * 32 + q * 8);
    }
    #pragma unroll
    for (int jt = 0; jt < 4; ++jt) {
        int n = wc * 64 + jt * 16 + m;
        #pragma unroll
        for (int ks = 0; ks < 4; ++ks)
            w2f[jt][ks] = *(const bf16x8*)(wsb + 16384 + n * 128 + ks * 32 + q * 8);
    }
    const float embv = (m < 3) ? wsf[WSF_EMB + b * 3 + m] : 0.0f;

    // conv source pointers (lane's 3 input channels: ic = 3q + i3)
    const float* src3[3];
    #pragma unroll
    for (int i3 = 0; i3 < 3; ++i3) {
        int ic = 3 * q + i3;
        src3[i3] = (ic < 3) ? (xg + (((size_t)b * 3 + ic) << 16))
                            : (hg + (((size_t)b * 9 + (ic - 3)) << 16));
    }
    // clamped y-row offsets + validity (uniform per block)
    int yoff[3]; bool yokk[3];
    #pragma unroll
    for (int ky = 0; ky < 3; ++ky) {
        int yy = y + ky - 1;
        yokk[ky] = (yy >= 0) && (yy < 256);
        yoff[ky] = (yokk[ky] ? yy : y) * 256;
    }

    // raw (unmasked, addr-clamped) tap loads for pixel pxl into tp[27]
    auto load_taps = [&](float (&tp)[27], int pxl) {
        const int xm1 = pxl - (pxl > 0);
        const int xp1 = pxl + (pxl < 255);
        #pragma unroll
        for (int i3 = 0; i3 < 3; ++i3) {
            #pragma unroll
            for (int ky = 0; ky < 3; ++ky) {
                const float* rp = src3[i3] + yoff[ky];
                tp[i3 * 9 + ky * 3 + 0] = rp[xm1];
                tp[i3 * 9 + ky * 3 + 1] = rp[pxl];
                tp[i3 * 9 + ky * 3 + 2] = rp[xp1];
            }
        }
    };

    const int w3sw = (m & 7) << 3;

    float tp[27];
    load_taps(tp, wv * 16 + m);     // it=0 prefetch (global only, pre-barrier ok)

    __syncthreads();   // staged LDS ready

    for (int it = 0; it < 4; ++it) {
        const int x0 = it * 64;
        const int px = x0 + wv * 16 + m;

        // ---- im2col staging: mask prefetched taps -> bf16 -> 4 x uint4 ----
        {
            const bool okl = (px > 0), okr = (px < 255);
            short* prow = bufA + (wv * 16 + m) * ACT_S + 32 * q;
            unsigned rr[16];
            rr[15] = 0u;                                  // shorts 30,31 pad
            #pragma unroll
            for (int i3 = 0; i3 < 3; ++i3) {
                float tm[9];
                #pragma unroll
                for (int ky = 0; ky < 3; ++ky) {
                    int o = i3 * 9 + ky * 3;
                    tm[ky * 3 + 0] = (yokk[ky] && okl) ? tp[o + 0] : 0.0f;
                    tm[ky * 3 + 1] = yokk[ky] ? tp[o + 1] : 0.0f;
                    tm[ky * 3 + 2] = (yokk[ky] && okr) ? tp[o + 2] : 0.0f;
                }
                rr[5 * i3 + 0] = pk2bf(tm[0], tm[1]);
                rr[5 * i3 + 1] = pk2bf(tm[2], tm[3]);
                rr[5 * i3 + 2] = pk2bf(tm[4], tm[5]);
                rr[5 * i3 + 3] = pk2bf(tm[6], tm[7]);
                rr[5 * i3 + 4] = pk2bf(tm[8], 0.0f);      // k=9 pad
            }
            #pragma unroll
            for (int w = 0; w < 4; ++w) {
                uint4 v; v.x = rr[4*w]; v.y = rr[4*w+1]; v.z = rr[4*w+2]; v.w = rr[4*w+3];
                *(uint4*)(prow + 8 * w) = v;
            }
        }
        __syncthreads();   // B1: im2col ready

        // prefetch it+1's taps now; latency hides under G1/G2/G3
        if (it < 3) load_taps(tp, px + 64);

        // ---- GEMM1 (r17 scheme): write h1S[px][ch] as one uint4 ----
        #pragma unroll
        for (int nt = 0; nt < 4; ++nt) {
            f32x4 c0 = *(const f32x4*)(bias_s + wv * 32 + 8 * q);
            f32x4 c1 = *(const f32x4*)(bias_s + wv * 32 + 8 * q + 4);
            #pragma unroll
            for (int ks = 0; ks < 4; ++ks) {
                bf16x8 p = *(const bf16x8*)(bufA + (nt * 16 + m) * ACT_S + ks * 32 + q * 8);
                c0 = __builtin_amdgcn_mfma_f32_16x16x32_bf16(w1f[0][ks], p, c0, 0, 0, 0);
                c1 = __builtin_amdgcn_mfma_f32_16x16x32_bf16(w1f[1][ks], p, c1, 0, 0, 0);
            }
            short* drow = h1S + (nt * 16 + m) * ACT_S + wv * 32 + 8 * q;
            uint4 pk4;
            pk4.x = pk2bf(fmaxf(c0[0], 0.f), fmaxf(c0[1], 0.f));
            pk4.y = pk2bf(fmaxf(c0[2], 0.f), fmaxf(c0[3], 0.f));
            pk4.z = pk2bf(fmaxf(c1[0], 0.f), fmaxf(c1[1], 0.f));
            pk4.w = pk2bf(fmaxf(c1[2], 0.f), fmaxf(c1[3], 0.f));
            *(uint4*)drow = pk4;
        }
        __syncthreads();   // B2: h1 ready; im2col fully read

        // ---- GEMM2 (4-way M-reuse): 4 M-tiles x 2 N-tiles; h2 -> bufA ----
        #pragma unroll
        for (int nt = 0; nt < 2; ++nt) {
            const int prow = (wp * 32 + nt * 16 + m) * ACT_S;
            f32x4 d0 = *(const f32x4*)(bias_s + 128 + wc * 64 + 16 * q + 0);
            f32x4 d1 = *(const f32x4*)(bias_s + 128 + wc * 64 + 16 * q + 4);
            f32x4 d2 = *(const f32x4*)(bias_s + 128 + wc * 64 + 16 * q + 8);
            f32x4 d3 = *(const f32x4*)(bias_s + 128 + wc * 64 + 16 * q + 12);
            #pragma unroll
            for (int ks = 0; ks < 4; ++ks) {
                bf16x8 a = *(const bf16x8*)(h1S + prow + ks * 32 + q * 8);
                d0 = __builtin_amdgcn_mfma_f32_16x16x32_bf16(w2f[0][ks], a, d0, 0, 0, 0);
                d1 = __builtin_amdgcn_mfma_f32_16x16x32_bf16(w2f[1][ks], a, d1, 0, 0, 0);
                d2 = __builtin_amdgcn_mfma_f32_16x16x32_bf16(w2f[2][ks], a, d2, 0, 0, 0);
                d3 = __builtin_amdgcn_mfma_f32_16x16x32_bf16(w2f[3][ks], a, d3, 0, 0, 0);
            }
            short* drow = bufA + prow + wc * 64 + 16 * q;
            uint4 A, B;
            A.x = pk2bf(fmaxf(d0[0], 0.f), fmaxf(d0[1], 0.f));
            A.y = pk2bf(fmaxf(d0[2], 0.f), fmaxf(d0[3], 0.f));
            A.z = pk2bf(fmaxf(d1[0], 0.f), fmaxf(d1[1], 0.f));
            A.w = pk2bf(fmaxf(d1[2], 0.f), fmaxf(d1[3], 0.f));
            B.x = pk2bf(fmaxf(d2[0], 0.f), fmaxf(d2[1], 0.f));
            B.y = pk2bf(fmaxf(d2[2], 0.f), fmaxf(d2[3], 0.f));
            B.z = pk2bf(fmaxf(d3[0], 0.f), fmaxf(d3[1], 0.f));
            B.w = pk2bf(fmaxf(d3[2], 0.f), fmaxf(d3[3], 0.f));
            *(uint4*)drow = A;
            *(uint4*)(drow + 8) = B;
        }
        __syncthreads();   // B3: h2 ready

        // ---- GEMM3: out = h2 . w3^T ; D col=oc, row=px; float4 store ----
        {
            f32x4 acc = {0.f, 0.f, 0.f, 0.f};
            #pragma unroll
            for (int ks = 0; ks < 4; ++ks) {
                bf16x8 a = *(const bf16x8*)(bufA + (wv * 16 + m) * ACT_S + ks * 32 + q * 8);
                bf16x8 w3k = *(const bf16x8*)(w3_s + (m << 7) + ((ks * 32 + q * 8) ^ w3sw));
                acc = __builtin_amdgcn_mfma_f32_16x16x32_bf16(a, w3k, acc, 0, 0, 0);
            }
            if (m < 12) {
                int xx0 = x0 + wv * 16 + q * 4;
                size_t idx;
                if (m < 3) {
                    idx = (size_t)NOISE_BASE + (((size_t)b * 3 + m) << 16) + (size_t)y * 256 + xx0;
                } else {
                    idx = (((size_t)b * 9 + (m - 3)) << 16) + (size_t)y * 256 + xx0;
                }
                f32x4 vst = {acc[0] + embv, acc[1] + embv, acc[2] + embv, acc[3] + embv};
                *(f32x4*)(outg + idx) = vst;
            }
        }
        __syncthreads();   // B4: bufA fully read; next staging may overwrite
    }
}

extern "C" void kernel_launch(void* const* d_in, const int* in_sizes, int n_in,
                              void* d_out, int out_size, void* d_ws, size_t ws_size,
                              hipStream_t stream) {
    const float* xg  = (const float*)d_in[0];
    const float* hg  = (const float*)d_in[1];
    const int*   tg  = (const int*)  d_in[2];
    const float* wpg = (const float*)d_in[3];
    const float* bpg = (const float*)d_in[4];
    const float* w1g = (const float*)d_in[5];
    const float* b1g = (const float*)d_in[6];
    const float* w2g = (const float*)d_in[7];
    const float* b2g = (const float*)d_in[8];
    const float* w3g = (const float*)d_in[9];
    const float* wtg = (const float*)d_in[10];
    const float* btg = (const float*)d_in[11];
    float* outg = (float*)d_out;
    short* wsb  = (short*)d_ws;
    float* wsf  = (float*)d_ws + WSF_OFF;

    prep_emb_kernel<<<146, 256, 0, stream>>>(wpg, bpg, w1g, b1g, w2g, b2g, w3g,
                                             tg, wtg, btg, wsb, wsf);
    canet_main<<<4096, 256, 0, stream>>>(xg, hg, wsb, wsf, outg);
}

// Round 18
// 200.647 us; speedup vs baseline: 2.5031x; 2.5031x over previous
//
#include <hip/hip_runtime.h>

// CANet fused kernel, round 23.
// Post-mortem r22: bound(256,3) + 96 frag regs = massive spill (FETCH 838MB,
// WRITE 479MB, 410us). Register law refined: fragment-heavy layouts don't fit
// beyond ~64+16 frag regs at 3 waves/SIMD. The 4-way-reuse family is dead on
// both axes (spill at 3w, occupancy at 2w).
// One untried implementation of the surviving hypothesis (cut LDS ops with
// occupancy HELD): w3 back to registers. w3_s was moved to LDS in r11 for an
// occupancy push later proven worthless; it costs 32 b128 reads/blk-iter
// (~15% of LDS ops) + ~2M conflict cycles. w3f[4] = +16 regs only; r5-r10
// precedent: identical layout ran 84 VGPR / 3 blocks / no spill.
// r23 = r17 + w3f in regs (w3_s deleted). Nothing else.
// Canaries (gating): WRITE 49152KB / FETCH ~74MB flat (spill), occ ~30%.
// Predict: conflicts 10.5->~8-9M; dur 116 -> 109-114. If flat & clean:
// hypothesis dead -> plateau, finalize best.

#define ACT_S 136     // 272 B rows (16B-aligned) for bufA/h1S [px][ch]
#define NOISE_BASE 9437184   // 16*9*65536

// d_ws shorts: Wf[128][128]@0, w2[128][128]@16384, w3[16][128]@32768 (2048)
// floats @ WSF_OFF: b1'[128]@0, b2[128]@128, emb[48]@256
#define WSF_OFF 17408
#define WSF_B1 0
#define WSF_B2 128
#define WSF_EMB 256

typedef short bf16x8 __attribute__((ext_vector_type(8)));
typedef float f32x4 __attribute__((ext_vector_type(4)));

__device__ __forceinline__ short f2bf(float f) {
    union { float f; unsigned u; } cv; cv.f = f;
    unsigned r = cv.u + 0x7FFFu + ((cv.u >> 16) & 1u);
    return (short)(r >> 16);
}
// pack two fp32 -> dword of two bf16 (round-half-up): lo16=bf(f0), hi16=bf(f1)
__device__ __forceinline__ unsigned pk2bf(float f0, float f1) {
    union { float f; unsigned u; } a, b; a.f = f0; b.f = f1;
    return __builtin_amdgcn_perm(b.u + 0x8000u, a.u + 0x8000u, 0x07060302u);
}

// fragment-row -> actual channel permutation (within each 32-ch wave block):
// f = base(32) + 16*j + i  ->  o = base + 8*(i>>2) + 4*j + (i&3)
__device__ __forceinline__ int permch(int f) {
    return (f & ~31) + 8 * ((f & 15) >> 2) + 4 * ((f >> 4) & 1) + (f & 3);
}

// ---------------- weight prep (fused Wf/b1') + time embedding ----------------
__global__ void prep_emb_kernel(const float* __restrict__ wpg, const float* __restrict__ bpg,
                                const float* __restrict__ w1g, const float* __restrict__ b1g,
                                const float* __restrict__ w2g, const float* __restrict__ b2g,
                                const float* __restrict__ w3g,
                                const int* __restrict__ t,
                                const float* __restrict__ wt, const float* __restrict__ bt,
                                short* __restrict__ wsb, float* __restrict__ wsf)
{
    const int bid = blockIdx.x, tid = threadIdx.x;
    if (bid < 64) {                       // Wf fragment rows (PERMUTED out-ch)
        int i = bid * 256 + tid;
        int f = i >> 7, kk = i & 127;
        int o = permch(f);
        int qq = kk >> 5, r = kk & 31;
        float v = 0.f;
        if (r < 30 && (r % 10) < 9) {
            int c3 = r / 10, k = r % 10;
            int ic = 3 * qq + c3;
            #pragma unroll
            for (int j = 0; j < 4; ++j)
                v += w1g[o * 48 + 4 * ic + j] * wpg[(4 * ic + j) * 9 + k];
        }
        wsb[i] = f2bf(v);
        return;
    }
    if (bid < 128) {                      // w2 fragment rows (PERMUTED out-ch)
        int i = (bid - 64) * 256 + tid;
        int f = i >> 7, col = i & 127;
        wsb[16384 + i] = f2bf(w2g[permch(f) * 128 + col]);
        return;
    }
    if (bid == 128) {                     // w3 [12][128] -> [16][128] pad
        for (int j = tid; j < 2048; j += 256)
            wsb[32768 + j] = (j < 1536) ? f2bf(w3g[j]) : (short)0;
        return;
    }
    if (bid == 129) {                     // b1' = b1 + w1.bp ; b2 copy (identity)
        if (tid < 128) {
            float s = b1g[tid];
            #pragma unroll 4
            for (int c = 0; c < 48; ++c) s += w1g[tid * 48 + c] * bpg[c];
            wsf[WSF_B1 + tid] = s;
        } else {
            wsf[WSF_B2 + (tid - 128)] = b2g[tid - 128];
        }
        return;
    }
    int b = bid - 130;                    // time embedding, one block per batch
    int lane = threadIdx.x;
    if (lane >= 64) return;
    float tv = (float)t[b];
    float s0 = 0.f, s1 = 0.f, s2 = 0.f;
    const float LOG1E4 = 9.210340371976184f;
    #pragma unroll
    for (int ii = 0; ii < 2; ++ii) {
        int i = lane + ii * 64;
        float invf = __expf(-LOG1E4 * (float)i * (1.0f / 128.0f));
        float ang = tv * invf;
        float sn = sinf(ang), cs = cosf(ang);
        float ss = sn / (1.0f + __expf(-sn));
        float sc = cs / (1.0f + __expf(-cs));
        s0 += ss * wt[0 * 256 + i] + sc * wt[0 * 256 + i + 128];
        s1 += ss * wt[1 * 256 + i] + sc * wt[1 * 256 + i + 128];
        s2 += ss * wt[2 * 256 + i] + sc * wt[2 * 256 + i + 128];
    }
    #pragma unroll
    for (int off = 32; off; off >>= 1) {
        s0 += __shfl_down(s0, off);
        s1 += __shfl_down(s1, off);
        s2 += __shfl_down(s2, off);
    }
    if (lane == 0) {
        wsf[WSF_EMB + b * 3 + 0] = s0 + bt[0];
        wsf[WSF_EMB + b * 3 + 1] = s1 + bt[1];
        wsf[WSF_EMB + b * 3 + 2] = s2 + bt[2];
    }
}

// ---------------- main fused kernel ----------------
// MFMA 16x16x32 (m89): A lane(i=lane&15,q) holds A[i][q*8+j]; B symmetric:
// lane holds B[q*8+j][i]. D: col(N)=lane&15, row(M)=q*4+r.
// With permch'd A-fragments, lane (m,q)'s c0(j=0)+c1(j=1) = chs base+8q+0..7
// (contiguous) for px=m -> one uint4 LDS write; positions stay ch-indexed.
__global__ __launch_bounds__(256, 3) void canet_main(
    const float* __restrict__ xg,   // (16,3,256,256)
    const float* __restrict__ hg,   // (16,9,256,256)
    const short* __restrict__ wsb,
    const float* __restrict__ wsf,
    float* __restrict__ outg)
{
    __shared__ __align__(16) short bufA[64 * ACT_S];   // im2col / h2
    __shared__ __align__(16) short h1S[64 * ACT_S];
    __shared__ __align__(16) float bias_s[256];        // b1' @0, b2 @128

    const int tid = threadIdx.x;
    const int b = blockIdx.x >> 8;
    const int y = blockIdx.x & 255;

    bias_s[tid] = wsf[WSF_B1 + tid];                   // b1'[0:128], b2[128:256]

    const int wv = tid >> 6;
    const int lane = tid & 63;
    const int m = lane & 15;
    const int q = lane >> 4;

    // ---- persistent weight fragments (Wf 32 + w2 32 + w3 16 = 80 regs) ----
    bf16x8 w1f[2][4], w2f[2][4], w3f[4];
    #pragma unroll
    for (int j = 0; j < 2; ++j) {
        int n = wv * 32 + j * 16 + m;
        #pragma unroll
        for (int ks = 0; ks < 4; ++ks) {
            w1f[j][ks] = *(const bf16x8*)(wsb + n * 128 + ks * 32 + q * 8);
            w2f[j][ks] = *(const bf16x8*)(wsb + 16384 + n * 128 + ks * 32 + q * 8);
        }
    }
    #pragma unroll
    for (int ks = 0; ks < 4; ++ks)
        w3f[ks] = *(const bf16x8*)(wsb + 32768 + m * 128 + ks * 32 + q * 8);
    const float embv = (m < 3) ? wsf[WSF_EMB + b * 3 + m] : 0.0f;

    // conv source pointers (lane's 3 input channels: ic = 3q + i3)
    const float* src3[3];
    #pragma unroll
    for (int i3 = 0; i3 < 3; ++i3) {
        int ic = 3 * q + i3;
        src3[i3] = (ic < 3) ? (xg + (((size_t)b * 3 + ic) << 16))
                            : (hg + (((size_t)b * 9 + (ic - 3)) << 16));
    }
    // clamped y-row offsets + validity (uniform per block)
    int yoff[3]; bool yokk[3];
    #pragma unroll
    for (int ky = 0; ky < 3; ++ky) {
        int yy = y + ky - 1;
        yokk[ky] = (yy >= 0) && (yy < 256);
        yoff[ky] = (yokk[ky] ? yy : y) * 256;
    }

    // raw (unmasked, addr-clamped) tap loads for pixel pxl into tp[27]
    auto load_taps = [&](float (&tp)[27], int pxl) {
        const int xm1 = pxl - (pxl > 0);
        const int xp1 = pxl + (pxl < 255);
        #pragma unroll
        for (int i3 = 0; i3 < 3; ++i3) {
            #pragma unroll
            for (int ky = 0; ky < 3; ++ky) {
                const float* rp = src3[i3] + yoff[ky];
                tp[i3 * 9 + ky * 3 + 0] = rp[xm1];
                tp[i3 * 9 + ky * 3 + 1] = rp[pxl];
                tp[i3 * 9 + ky * 3 + 2] = rp[xp1];
            }
        }
    };

    float tp[27];
    load_taps(tp, wv * 16 + m);     // it=0 prefetch (global only, pre-barrier ok)

    __syncthreads();   // staged LDS ready

    for (int it = 0; it < 4; ++it) {
        const int x0 = it * 64;
        const int px = x0 + wv * 16 + m;

        // ---- im2col staging: mask prefetched taps -> bf16 -> 4 x uint4 ----
        {
            const bool okl = (px > 0), okr = (px < 255);
            short* prow = bufA + (wv * 16 + m) * ACT_S + 32 * q;
            unsigned rr[16];
            rr[15] = 0u;                                  // shorts 30,31 pad
            #pragma unroll
            for (int i3 = 0; i3 < 3; ++i3) {
                float tm[9];
                #pragma unroll
                for (int ky = 0; ky < 3; ++ky) {
                    int o = i3 * 9 + ky * 3;
                    tm[ky * 3 + 0] = (yokk[ky] && okl) ? tp[o + 0] : 0.0f;
                    tm[ky * 3 + 1] = yokk[ky] ? tp[o + 1] : 0.0f;
                    tm[ky * 3 + 2] = (yokk[ky] && okr) ? tp[o + 2] : 0.0f;
                }
                rr[5 * i3 + 0] = pk2bf(tm[0], tm[1]);
                rr[5 * i3 + 1] = pk2bf(tm[2], tm[3]);
                rr[5 * i3 + 2] = pk2bf(tm[4], tm[5]);
                rr[5 * i3 + 3] = pk2bf(tm[6], tm[7]);
                rr[5 * i3 + 4] = pk2bf(tm[8], 0.0f);      // k=9 pad
            }
            #pragma unroll
            for (int w = 0; w < 4; ++w) {
                uint4 v; v.x = rr[4*w]; v.y = rr[4*w+1]; v.z = rr[4*w+2]; v.w = rr[4*w+3];
                *(uint4*)(prow + 8 * w) = v;
            }
        }
        __syncthreads();   // B1: im2col ready

        // prefetch it+1's taps now; latency hides under G1/G2/G3
        if (it < 3) load_taps(tp, px + 64);

        // ---- GEMM1 (swapped, permuted): write h1S[px][ch] as one uint4 ----
        #pragma unroll
        for (int nt = 0; nt < 4; ++nt) {
            f32x4 c0 = *(const f32x4*)(bias_s + wv * 32 + 8 * q);
            f32x4 c1 = *(const f32x4*)(bias_s + wv * 32 + 8 * q + 4);
            #pragma unroll
            for (int ks = 0; ks < 4; ++ks) {
                bf16x8 p = *(const bf16x8*)(bufA + (nt * 16 + m) * ACT_S + ks * 32 + q * 8);
                c0 = __builtin_amdgcn_mfma_f32_16x16x32_bf16(w1f[0][ks], p, c0, 0, 0, 0);
                c1 = __builtin_amdgcn_mfma_f32_16x16x32_bf16(w1f[1][ks], p, c1, 0, 0, 0);
            }
            short* drow = h1S + (nt * 16 + m) * ACT_S + wv * 32 + 8 * q;
            uint4 pk4;
            pk4.x = pk2bf(fmaxf(c0[0], 0.f), fmaxf(c0[1], 0.f));
            pk4.y = pk2bf(fmaxf(c0[2], 0.f), fmaxf(c0[3], 0.f));
            pk4.z = pk2bf(fmaxf(c1[0], 0.f), fmaxf(c1[1], 0.f));
            pk4.w = pk2bf(fmaxf(c1[2], 0.f), fmaxf(c1[3], 0.f));
            *(uint4*)drow = pk4;
        }
        __syncthreads();   // B2: h1 ready; im2col fully read

        // ---- GEMM2 (swapped, permuted): write h2 -> bufA as one uint4 ----
        #pragma unroll
        for (int nt = 0; nt < 4; ++nt) {
            f32x4 c0 = *(const f32x4*)(bias_s + 128 + wv * 32 + 8 * q);
            f32x4 c1 = *(const f32x4*)(bias_s + 128 + wv * 32 + 8 * q + 4);
            #pragma unroll
            for (int ks = 0; ks < 4; ++ks) {
                bf16x8 a = *(const bf16x8*)(h1S + (nt * 16 + m) * ACT_S + ks * 32 + q * 8);
                c0 = __builtin_amdgcn_mfma_f32_16x16x32_bf16(w2f[0][ks], a, c0, 0, 0, 0);
                c1 = __builtin_amdgcn_mfma_f32_16x16x32_bf16(w2f[1][ks], a, c1, 0, 0, 0);
            }
            short* drow = bufA + (nt * 16 + m) * ACT_S + wv * 32 + 8 * q;
            uint4 pk4;
            pk4.x = pk2bf(fmaxf(c0[0], 0.f), fmaxf(c0[1], 0.f));
            pk4.y = pk2bf(fmaxf(c0[2], 0.f), fmaxf(c0[3], 0.f));
            pk4.z = pk2bf(fmaxf(c1[0], 0.f), fmaxf(c1[1], 0.f));
            pk4.w = pk2bf(fmaxf(c1[2], 0.f), fmaxf(c1[3], 0.f));
            *(uint4*)drow = pk4;
        }
        __syncthreads();   // B3: h2 ready

        // ---- GEMM3: out = h2 . w3^T ; D col=oc, row=px; float4 store ----
        {
            f32x4 acc = {0.f, 0.f, 0.f, 0.f};
            #pragma unroll
            for (int ks = 0; ks < 4; ++ks) {
                bf16x8 a = *(const bf16x8*)(bufA + (wv * 16 + m) * ACT_S + ks * 32 + q * 8);
                acc = __builtin_amdgcn_mfma_f32_16x16x32_bf16(a, w3f[ks], acc, 0, 0, 0);
            }
            if (m < 12) {
                int xx0 = x0 + wv * 16 + q * 4;
                size_t idx;
                if (m < 3) {
                    idx = (size_t)NOISE_BASE + (((size_t)b * 3 + m) << 16) + (size_t)y * 256 + xx0;
                } else {
                    idx = (((size_t)b * 9 + (m - 3)) << 16) + (size_t)y * 256 + xx0;
                }
                f32x4 vst = {acc[0] + embv, acc[1] + embv, acc[2] + embv, acc[3] + embv};
                *(f32x4*)(outg + idx) = vst;
            }
        }
        __syncthreads();   // B4: bufA fully read; next staging may overwrite
    }
}

extern "C" void kernel_launch(void* const* d_in, const int* in_sizes, int n_in,
                              void* d_out, int out_size, void* d_ws, size_t ws_size,
                              hipStream_t stream) {
    const float* xg  = (const float*)d_in[0];
    const float* hg  = (const float*)d_in[1];
    const int*   tg  = (const int*)  d_in[2];
    const float* wpg = (const float*)d_in[3];
    const float* bpg = (const float*)d_in[4];
    const float* w1g = (const float*)d_in[5];
    const float* b1g = (const float*)d_in[6];
    const float* w2g = (const float*)d_in[7];
    const float* b2g = (const float*)d_in[8];
    const float* w3g = (const float*)d_in[9];
    const float* wtg = (const float*)d_in[10];
    const float* btg = (const float*)d_in[11];
    float* outg = (float*)d_out;
    short* wsb  = (short*)d_ws;
    float* wsf  = (float*)d_ws + WSF_OFF;

    prep_emb_kernel<<<146, 256, 0, stream>>>(wpg, bpg, w1g, b1g, w2g, b2g, w3g,
                                             tg, wtg, btg, wsb, wsf);
    canet_main<<<4096, 256, 0, stream>>>(xg, hg, wsb, wsf, outg);
}